// Round 14
// baseline (109.926 us; speedup 1.0000x reference)
//
#include <hip/hip_runtime.h>
#include <hip/hip_bf16.h>

typedef unsigned short u16;
typedef unsigned int   u32;

typedef __attribute__((ext_vector_type(8))) short bfrag;   // 8 bf16 (4 VGPRs)
typedef __attribute__((ext_vector_type(4))) float f32x4;   // MFMA acc

static __device__ __forceinline__ u16 f2bf(float f) {
    u32 u = __float_as_uint(f);
    return (u16)((u + 0x7fffu + ((u >> 16) & 1u)) >> 16);   // RNE
}
static __device__ __forceinline__ u32 pk2(float a, float b) {
    return (u32)f2bf(a) | ((u32)f2bf(b) << 16);
}
static __device__ __forceinline__ float bf2f(u16 h) {
    return __uint_as_float((u32)h << 16);
}

#define AS1 __attribute__((address_space(1)))
#define AS3 __attribute__((address_space(3)))
static __device__ __forceinline__ void gload_lds16(const u16* g, u16* l) {
    __builtin_amdgcn_global_load_lds((const AS1 u32*)g, (AS3 u32*)l, 16, 0, 0);
}

// ---------------- merged prep: abf (padded bf16 A), wt (conv W^T), wh (head W^T)
__global__ __launch_bounds__(256) void prep_all_k(
    const float* __restrict__ data,   // [8,64,64,512]
    const float* __restrict__ wb,     // [3,3,512,256]
    const float* __restrict__ wc,     // [256,9]
    const float* __restrict__ wr,     // [256,36]
    u16* __restrict__ abf,            // [8][66][66][512]
    u16* __restrict__ wt,             // [9][256][512]
    u16* __restrict__ wh)             // [64][256]
{
    int b = blockIdx.x, tid = threadIdx.x;
    if (b < 8712) {
        int gid = b * 256 + tid;                  // < 2,230,272
        int ch8 = gid & 63;
        int row = gid >> 6;                       // < 8*66*66
        int img = row / 4356;
        int rem = row - img * 4356;
        int py  = rem / 66;
        int px  = rem - py * 66;
        uint4 o;
        if (py == 0 || py == 65 || px == 0 || px == 65) {
            o = make_uint4(0u, 0u, 0u, 0u);
        } else {
            const float4* s = (const float4*)(data +
                ((size_t)((img << 12) + ((py - 1) << 6) + (px - 1)) << 9) + (ch8 << 3));
            float4 v0 = s[0], v1 = s[1];
            o = make_uint4(pk2(v0.x, v0.y), pk2(v0.z, v0.w),
                           pk2(v1.x, v1.y), pk2(v1.z, v1.w));
        }
        *(uint4*)(abf + ((size_t)row << 9) + (ch8 << 3)) = o;
    } else if (b < 13320) {
        int i  = (b - 8712) * 256 + tid;          // < 1,179,648
        int ci = i & 511;
        int co = (i >> 9) & 255;
        int pos = i >> 17;
        wt[i] = f2bf(wb[(size_t)((pos << 9) + ci) * 256 + co]);
    } else {
        int i = (b - 13320) * 256 + tid;          // < 16384
        int ch = i >> 8, c = i & 255;
        float v = 0.f;
        if (ch < 36)      v = wr[c * 36 + ch];
        else if (ch < 45) v = wc[c * 9 + ch - 36];
        wh[i] = f2bf(v);
    }
}

// ---------------- main GEMM: implicit 3x3 conv, counted-vmcnt on r13's cadence
// 128 pix x 128 co tile, 256 thr = 4 waves (2Mx2N), 512 blocks (2/CU), LDS 64KB.
// 72 K-64 units; 2 buffers; stage(h+1) issued, then s_waitcnt vmcnt(8) (stage(h)
// landed, h+1's 8 in flight) + raw s_barrier; NO vmcnt(0) drain in main loop.
__global__ __launch_bounds__(256, 2) void gemm_k(
    const u16*   __restrict__ abf,    // [8][66][66][512] bf16 padded
    const u16*   __restrict__ wt,     // [9][256][512] bf16
    const float* __restrict__ bb,     // [256]
    u16*         __restrict__ feat)   // [32768][256] bf16
{
    __shared__ u16 As[2][128 * 64];   // 2 x 16 KB
    __shared__ u16 Bs[2][128 * 64];   // 2 x 16 KB

    int bid = blockIdx.x;                          // 512
    int wg  = ((bid & 7) << 6) | (bid >> 3);       // XCD swizzle: img = bid&7
    int mt  = wg >> 1, nt = wg & 1;
    int pm0 = mt << 7, cn0 = nt << 7;
    int img = mt >> 5;
    int y0  = (mt & 31) << 1;

    int tid = threadIdx.x, lane = tid & 63, w = tid >> 6;
    int wm2 = (w >> 1) << 6, wn2 = (w & 1) << 6;
    int fr = lane & 15, fg = lane >> 4;

    // staging: per K-64 unit, A 1024 + B 1024 slots of 16B (4+4 per thread)
    const u16* pA[4]; const u16* pB[4];
    int ldsOff[4];
    #pragma unroll
    for (int i = 0; i < 4; ++i) {
        int slot = i * 256 + w * 64 + lane;        // 0..1023
        int row  = slot >> 3, g = slot & 7;
        int gs   = g ^ (row & 7);                  // inverse swizzle on source
        int y = y0 + (row >> 6), x = row & 63;
        pA[i] = abf + ((size_t)((img * 66 + y) * 66 + x) << 9) + (gs << 3);
        pB[i] = wt  + ((size_t)(cn0 + row) << 9) + (gs << 3);
        ldsOff[i] = (i * 256 + w * 64) << 3;       // u16 index, wave-uniform
    }

    // fragment LDS offsets (u16 idx), stride 64: zero-conflict layout (r9/r13)
    int aoff[2][4], boff[2][4];
    #pragma unroll
    for (int kk = 0; kk < 2; ++kk)
        #pragma unroll
        for (int t = 0; t < 4; ++t) {
            int ra = wm2 + (t << 4) + fr;
            int rb = wn2 + (t << 4) + fr;
            int q  = (kk << 2) | fg;
            aoff[kk][t] = (ra << 6) + ((q ^ (ra & 7)) << 3);
            boff[kk][t] = (rb << 6) + ((q ^ (rb & 7)) << 3);
        }

    f32x4 acc[4][4] = {};

    // h = kb*18 + pos*2 + half  (kb-outer keeps A L2-hot)
    auto stage = [&](int h, int buf) {
        int kb  = h / 18;
        int rem = h - kb * 18;
        int pos = rem >> 1;
        int py  = pos / 3, px = pos - py * 3;
        size_t ko  = ((size_t)kb << 7) + ((size_t)(rem & 1) << 6);
        size_t soA = (((size_t)(py * 66 + px)) << 9) + ko;
        size_t soB = (((size_t)pos) << 17) + ko;
        u16* ad = &As[buf][0];
        u16* bd = &Bs[buf][0];
        #pragma unroll
        for (int i = 0; i < 4; ++i) gload_lds16(pA[i] + soA, ad + ldsOff[i]);
        #pragma unroll
        for (int i = 0; i < 4; ++i) gload_lds16(pB[i] + soB, bd + ldsOff[i]);
    };

    stage(0, 0);                                   // 8 loads in flight
    int cur = 0;
    #pragma unroll 1
    for (int h = 0; h < 72; ++h) {
        // WAR-safe: buf cur^1 was last read in compute(h-1), closed by the
        // trailing barrier of iteration h-1.
        if (h < 71) {
            stage(h + 1, cur ^ 1);
            asm volatile("s_waitcnt vmcnt(8)" ::: "memory");   // stage(h) landed
        } else {
            asm volatile("s_waitcnt vmcnt(0)" ::: "memory");
        }
        __builtin_amdgcn_sched_barrier(0);
        __builtin_amdgcn_s_barrier();              // all waves' stage(h) landed

        const u16* a = &As[cur][0];
        const u16* bp = &Bs[cur][0];
        __builtin_amdgcn_s_setprio(1);
        #pragma unroll
        for (int kk = 0; kk < 2; ++kk) {
            bfrag av[4], bv[4];
            #pragma unroll
            for (int t = 0; t < 4; ++t) {
                av[t] = *(const bfrag*)(a  + aoff[kk][t]);
                bv[t] = *(const bfrag*)(bp + boff[kk][t]);
            }
            #pragma unroll
            for (int mi = 0; mi < 4; ++mi)
                #pragma unroll
                for (int ni = 0; ni < 4; ++ni)
                    acc[mi][ni] = __builtin_amdgcn_mfma_f32_16x16x32_bf16(
                        av[mi], bv[ni], acc[mi][ni], 0, 0, 0);
        }
        __builtin_amdgcn_s_setprio(0);
        __builtin_amdgcn_s_barrier();              // compute(h) reads closed
        cur ^= 1;
    }

    // epilogue: bias + relu -> feat[pix][co] bf16
    #pragma unroll
    for (int ni = 0; ni < 4; ++ni) {
        int co = cn0 + wn2 + (ni << 4) + fr;
        float bias = bb[co];
        #pragma unroll
        for (int mi = 0; mi < 4; ++mi) {
            int pixb = pm0 + wm2 + (mi << 4) + (fg << 2);
            #pragma unroll
            for (int r = 0; r < 4; ++r) {
                float v = fmaxf(acc[mi][ni][r] + bias, 0.f);
                feat[(size_t)(pixb + r) * 256 + co] = f2bf(v);
            }
        }
    }
}

// ---------------- head: MFMA GEMM [64pix x 48ch x 256] + sigmoid/mask/pack
__global__ __launch_bounds__(256, 2) void head_k(
    const u16*   __restrict__ feat,   // [32768][256] bf16
    const u16*   __restrict__ wh,     // [64][256] bf16 (45 live)
    const float* __restrict__ bc,     // [9]
    const float* __restrict__ br,     // [36]
    float*       __restrict__ out)    // [32768,45]
{
    __shared__ union {
        u16   ft[64 * 256];           // 32 KB, granule-swizzled
        float raw[64 * 45];           // 11.5 KB
    } sm;

    int bid = blockIdx.x;                          // 512
    int wg  = ((bid & 7) << 6) | (bid >> 3);       // img = bid&7
    int pb  = wg << 6;                             // pixel base

    int tid = threadIdx.x, lane = tid & 63, w = tid >> 6;
    int fr = lane & 15, fg = lane >> 4;
    int wm = w << 4;                               // wave's 16-pix slice

    bfrag bv[3][8];
    #pragma unroll
    for (int nt = 0; nt < 3; ++nt)
        #pragma unroll
        for (int kk = 0; kk < 8; ++kk)
            bv[nt][kk] = *(const bfrag*)(wh + ((nt << 4) + fr) * 256 + (kk << 5) + (fg << 3));

    const u16* fbase = feat + ((size_t)pb << 8);
    #pragma unroll
    for (int i = 0; i < 8; ++i) {
        int slot = i * 256 + tid;                  // 0..2047
        int row  = slot >> 5, g = slot & 31;
        int gs   = g ^ (row & 7);
        gload_lds16(fbase + (row << 8) + (gs << 3), &sm.ft[(i * 256 + w * 64) << 3]);
    }
    __syncthreads();

    f32x4 acc[3] = {};
    #pragma unroll
    for (int kk = 0; kk < 8; ++kk) {
        int row = wm + fr;
        int ga  = (kk << 2) | fg;
        bfrag av = *(const bfrag*)&sm.ft[(row << 8) + ((ga ^ (row & 7)) << 3)];
        #pragma unroll
        for (int nt = 0; nt < 3; ++nt)
            acc[nt] = __builtin_amdgcn_mfma_f32_16x16x32_bf16(av, bv[nt][kk], acc[nt], 0, 0, 0);
    }
    __syncthreads();                               // ft reads done (union reuse)

    #pragma unroll
    for (int nt = 0; nt < 3; ++nt) {
        int ch = (nt << 4) + fr;
        if (ch < 45) {
            float bias = (ch < 36) ? br[ch] : bc[ch - 36];
            int pix = wm + (fg << 2);
            #pragma unroll
            for (int r = 0; r < 4; ++r)
                sm.raw[(pix + r) * 45 + ch] = acc[nt][r] + bias;
        }
    }
    __syncthreads();

    {
        int pix = tid >> 2, q = tid & 3;
        const float* rp = &sm.raw[pix * 45];
        float* op = out + (size_t)(pb + pix) * 45;
        int na = (q == 3) ? 3 : 2;
        int a0 = (q == 3) ? 6 : (q << 1);
        for (int t = 0; t < na; ++t) {
            int a = a0 + t;
            float lg  = rp[36 + a];
            float obj = 1.f / (1.f + __expf(-lg));
            float b0 = rp[4*a], b1 = rp[4*a+1], b2 = rp[4*a+2], b3 = rp[4*a+3];
            bool m = (obj > 0.7f) && (b2 > 10.f) && (b3 > 10.f);
            op[4*a    ] = m ? b0 : 0.f;
            op[4*a + 1] = m ? b1 : 0.f;
            op[4*a + 2] = m ? b2 : 0.f;
            op[4*a + 3] = m ? b3 : 0.f;
            op[36 + a ] = obj;
        }
    }
}

// ================= fallback (r6): fused conv+head, needs only wt (or nothing)
__global__ __launch_bounds__(256) void prep_w_k(const float* __restrict__ wb,
                                                u16* __restrict__ wt)
{
    int i  = blockIdx.x * 256 + threadIdx.x;
    int ci = i & 511;
    int co = (i >> 9) & 255;
    int pos = i >> 17;
    wt[i] = f2bf(wb[(size_t)((pos << 9) + ci) * 256 + co]);
}

union FbSmem {
    u16   hal[3 * 66 * 64];
    u16   ft[256][64];
    float raw[64 * 45];
};

template<int WMODE>
__global__ __launch_bounds__(256, 2) void fb_k(
    const float* __restrict__ data, const u16* __restrict__ wt,
    const float* __restrict__ wb, const float* __restrict__ bb,
    const float* __restrict__ wc, const float* __restrict__ bc,
    const float* __restrict__ wr, const float* __restrict__ br,
    float* __restrict__ out)
{
    __shared__ FbSmem sm;
    int bid = blockIdx.x;
    int wg  = ((bid & 7) << 6) | (bid >> 3);
    int pm0 = wg << 6;
    int img = wg >> 6;
    int y0  = wg & 63;
    int tid = threadIdx.x, lane = tid & 63, wid = tid >> 6;
    int wn = wid << 6;
    int fr = lane & 15, fg = lane >> 4;
    f32x4 acc[4][4] = {};

    #pragma unroll 1
    for (int cb = 0; cb < 8; ++cb) {
        __syncthreads();
        #pragma unroll
        for (int t = 0; t < 3; ++t) {
            int lin = t * 256 + tid;
            int row = lin >> 8, col = (lin >> 2) & 63, cq = lin & 3;
            int sy = y0 + row - 1;
            bool ok = (sy >= 0) && (sy < 64);
            float4 v0, v1, v2, v3;
            if (ok) {
                const float4* s = (const float4*)(data +
                    ((size_t)((img << 12) + (sy << 6) + col) << 9) + (cb << 6) + (cq << 4));
                v0 = s[0]; v1 = s[1]; v2 = s[2]; v3 = s[3];
            } else { v0 = v1 = v2 = v3 = make_float4(0.f, 0.f, 0.f, 0.f); }
            int hc = col + 1;
            u16* base = &sm.hal[(row * 66 + hc) << 6];
            int g0 = ((cq << 1) | 0) ^ (hc & 7);
            int g1 = ((cq << 1) | 1) ^ (hc & 7);
            *(uint4*)&base[g0 << 3] = make_uint4(pk2(v0.x,v0.y), pk2(v0.z,v0.w),
                                                 pk2(v1.x,v1.y), pk2(v1.z,v1.w));
            *(uint4*)&base[g1 << 3] = make_uint4(pk2(v2.x,v2.y), pk2(v2.z,v2.w),
                                                 pk2(v3.x,v3.y), pk2(v3.z,v3.w));
        }
        if (tid < 48) {
            int zr = tid >> 4, zrem = tid & 15;
            int zc = (zrem >> 3) ? 65 : 0, zg = zrem & 7;
            *(uint4*)&sm.hal[(((zr * 66 + zc) << 3) | zg) << 3] = make_uint4(0,0,0,0);
        }
        __syncthreads();

        #pragma unroll
        for (int pos = 0; pos < 9; ++pos) {
            int dy = pos / 3 - 1, dx = pos % 3 - 1;
            bfrag bv[2][4];
            if (WMODE == 0) {
                #pragma unroll
                for (int kk = 0; kk < 2; ++kk)
                    #pragma unroll
                    for (int i = 0; i < 4; ++i)
                        bv[kk][i] = *(const bfrag*)(wt + ((size_t)pos << 17) +
                            ((size_t)(wn + (i << 4) + fr) << 9) + (cb << 6) +
                            (kk << 5) + (fg << 3));
            } else {
                #pragma unroll
                for (int kk = 0; kk < 2; ++kk)
                    #pragma unroll
                    for (int i = 0; i < 4; ++i) {
                        int co = wn + (i << 4) + fr;
                        const float* s = wb +
                            (size_t)((pos << 9) + (cb << 6) + (kk << 5) + (fg << 3)) * 256 + co;
                        union { short sh[8]; bfrag v; } tb;
                        #pragma unroll
                        for (int j = 0; j < 8; ++j) tb.sh[j] = (short)f2bf(s[(size_t)j << 8]);
                        bv[kk][i] = tb.v;
                    }
            }
            int hr = dy + 1;
            bfrag av[2][4];
            #pragma unroll
            for (int kk = 0; kk < 2; ++kk)
                #pragma unroll
                for (int i = 0; i < 4; ++i) {
                    int hc = (i << 4) + fr + dx + 1;
                    int g  = ((kk << 2) | fg) ^ (hc & 7);
                    av[kk][i] = *(const bfrag*)&sm.hal[(((hr * 66 + hc) << 3) | g) << 3];
                }
            #pragma unroll
            for (int kk = 0; kk < 2; ++kk)
                #pragma unroll
                for (int mi = 0; mi < 4; ++mi)
                    #pragma unroll
                    for (int ni = 0; ni < 4; ++ni)
                        acc[mi][ni] = __builtin_amdgcn_mfma_f32_16x16x32_bf16(
                            av[kk][mi], bv[kk][ni], acc[mi][ni], 0, 0, 0);
        }
    }
    __syncthreads();

    #pragma unroll
    for (int ni = 0; ni < 4; ++ni) {
        int co = wn + (ni << 4) + fr;
        float bias = bb[co];
        int rot = (co & 15) << 2;
        #pragma unroll
        for (int mi = 0; mi < 4; ++mi) {
            int pb  = (mi << 4) + (fg << 2);
            int col = (pb + rot) & 63;
            float r0 = fmaxf(acc[mi][ni][0] + bias, 0.f);
            float r1 = fmaxf(acc[mi][ni][1] + bias, 0.f);
            float r2 = fmaxf(acc[mi][ni][2] + bias, 0.f);
            float r3 = fmaxf(acc[mi][ni][3] + bias, 0.f);
            *(uint2*)&sm.ft[co][col] = make_uint2(pk2(r0, r1), pk2(r2, r3));
        }
    }
    __syncthreads();

    int wchx = __builtin_amdgcn_readfirstlane(wid) * 12;
    float a12[12];
    #pragma unroll
    for (int j = 0; j < 12; ++j) {
        int ch = wchx + j;
        a12[j] = (ch < 36) ? br[ch] : ((ch < 45) ? bc[ch - 36] : 0.f);
    }
    #pragma unroll 4
    for (int c = 0; c < 256; ++c) {
        int col = (lane + ((c & 15) << 2)) & 63;
        float f = bf2f(sm.ft[c][col]);
        #pragma unroll
        for (int j = 0; j < 12; ++j) {
            int ch = wchx + j;
            if (ch < 36)      a12[j] = fmaf(f, wr[c * 36 + ch], a12[j]);
            else if (ch < 45) a12[j] = fmaf(f, wc[c * 9 + ch - 36], a12[j]);
        }
    }
    __syncthreads();
    #pragma unroll
    for (int j = 0; j < 12; ++j) {
        int ch = wchx + j;
        if (ch < 45) sm.raw[lane * 45 + ch] = a12[j];
    }
    __syncthreads();
    {
        int pix = tid >> 2, q = tid & 3;
        const float* rp = &sm.raw[pix * 45];
        float* op = out + (size_t)(pm0 + pix) * 45;
        int na = (q == 3) ? 3 : 2;
        int a0 = (q == 3) ? 6 : (q << 1);
        for (int t = 0; t < na; ++t) {
            int a = a0 + t;
            float lg  = rp[36 + a];
            float obj = 1.f / (1.f + __expf(-lg));
            float b0 = rp[4*a], b1 = rp[4*a+1], b2 = rp[4*a+2], b3 = rp[4*a+3];
            bool m = (obj > 0.7f) && (b2 > 10.f) && (b3 > 10.f);
            op[4*a    ] = m ? b0 : 0.f;
            op[4*a + 1] = m ? b1 : 0.f;
            op[4*a + 2] = m ? b2 : 0.f;
            op[4*a + 3] = m ? b3 : 0.f;
            op[36 + a ] = obj;
        }
    }
}

extern "C" void kernel_launch(void* const* d_in, const int* in_sizes, int n_in,
                              void* d_out, int out_size, void* d_ws, size_t ws_size,
                              hipStream_t stream)
{
    const float* data = (const float*)d_in[0];
    const float* wb   = (const float*)d_in[1];
    const float* bb   = (const float*)d_in[2];
    const float* wc   = (const float*)d_in[3];
    const float* bcl  = (const float*)d_in[4];
    const float* wr   = (const float*)d_in[5];
    const float* brg  = (const float*)d_in[6];
    float* out = (float*)d_out;

    const size_t ABF_B  = (size_t)8 * 66 * 66 * 512 * 2;   // 35,684,352
    const size_t WT_B   = (size_t)9 * 256 * 512 * 2;       //  2,359,296
    const size_t FEAT_B = (size_t)32768 * 256 * 2;         // 16,777,216
    const size_t WH_B   = (size_t)64 * 256 * 2;            //     32,768

    if (ws_size >= ABF_B + WT_B + FEAT_B + WH_B) {
        u16* abf  = (u16*)d_ws;
        u16* wt   = (u16*)((char*)d_ws + ABF_B);
        u16* feat = (u16*)((char*)d_ws + ABF_B + WT_B);
        u16* wh   = (u16*)((char*)d_ws + ABF_B + WT_B + FEAT_B);
        prep_all_k<<<13384, 256, 0, stream>>>(data, wb, wc, wr, abf, wt, wh);
        gemm_k<<<512, 256, 0, stream>>>(abf, wt, bb, feat);
        head_k<<<512, 256, 0, stream>>>(feat, wh, bcl, brg, out);
    } else if (ws_size >= WT_B) {
        u16* wt = (u16*)d_ws;
        prep_w_k<<<4608, 256, 0, stream>>>(wb, wt);
        fb_k<0><<<512, 256, 0, stream>>>(data, wt, wb, bb, wc, bcl, wr, brg, out);
    } else {
        fb_k<1><<<512, 256, 0, stream>>>(data, (const u16*)nullptr, wb,
                                         bb, wc, bcl, wr, brg, out);
    }
}

// Round 15
// 103.250 us; speedup vs baseline: 1.0647x; 1.0647x over previous
//
#include <hip/hip_runtime.h>
#include <hip/hip_bf16.h>

typedef unsigned short u16;
typedef unsigned int   u32;

typedef __attribute__((ext_vector_type(8))) short bfrag;   // 8 bf16 (4 VGPRs)
typedef __attribute__((ext_vector_type(4))) float f32x4;   // MFMA acc

static __device__ __forceinline__ u16 f2bf(float f) {
    u32 u = __float_as_uint(f);
    return (u16)((u + 0x7fffu + ((u >> 16) & 1u)) >> 16);   // RNE
}
static __device__ __forceinline__ u32 pk2(float a, float b) {
    return (u32)f2bf(a) | ((u32)f2bf(b) << 16);
}
static __device__ __forceinline__ float bf2f(u16 h) {
    return __uint_as_float((u32)h << 16);
}

#define AS1 __attribute__((address_space(1)))
#define AS3 __attribute__((address_space(3)))
static __device__ __forceinline__ void gload_lds16(const u16* g, u16* l) {
    __builtin_amdgcn_global_load_lds((const AS1 u32*)g, (AS3 u32*)l, 16, 0, 0);
}

// ---------------- merged prep: abf (padded bf16 A), wt (conv W^T), wh (head W^T)
__global__ __launch_bounds__(256) void prep_all_k(
    const float* __restrict__ data,   // [8,64,64,512]
    const float* __restrict__ wb,     // [3,3,512,256]
    const float* __restrict__ wc,     // [256,9]
    const float* __restrict__ wr,     // [256,36]
    u16* __restrict__ abf,            // [8][66][66][512]
    u16* __restrict__ wt,             // [9][256][512]
    u16* __restrict__ wh)             // [64][256]
{
    int b = blockIdx.x, tid = threadIdx.x;
    if (b < 8712) {
        int gid = b * 256 + tid;                  // < 2,230,272
        int ch8 = gid & 63;
        int row = gid >> 6;                       // < 8*66*66
        int img = row / 4356;
        int rem = row - img * 4356;
        int py  = rem / 66;
        int px  = rem - py * 66;
        uint4 o;
        if (py == 0 || py == 65 || px == 0 || px == 65) {
            o = make_uint4(0u, 0u, 0u, 0u);
        } else {
            const float4* s = (const float4*)(data +
                ((size_t)((img << 12) + ((py - 1) << 6) + (px - 1)) << 9) + (ch8 << 3));
            float4 v0 = s[0], v1 = s[1];
            o = make_uint4(pk2(v0.x, v0.y), pk2(v0.z, v0.w),
                           pk2(v1.x, v1.y), pk2(v1.z, v1.w));
        }
        *(uint4*)(abf + ((size_t)row << 9) + (ch8 << 3)) = o;
    } else if (b < 13320) {
        int i  = (b - 8712) * 256 + tid;          // < 1,179,648
        int ci = i & 511;
        int co = (i >> 9) & 255;
        int pos = i >> 17;
        wt[i] = f2bf(wb[(size_t)((pos << 9) + ci) * 256 + co]);
    } else {
        int i = (b - 13320) * 256 + tid;          // < 16384
        int ch = i >> 8, c = i & 255;
        float v = 0.f;
        if (ch < 36)      v = wr[c * 36 + ch];
        else if (ch < 45) v = wc[c * 9 + ch - 36];
        wh[i] = f2bf(v);
    }
}

// ---------------- main GEMM: implicit 3x3 conv (r13 best: 74.6us, MfmaUtil 45%)
// r10's barrier cadence (36 step-pairs, 64 MFMA/wave between barriers) +
// r10's kb-outer ordering (L2-hot A) + r9's BK=64 buffer layout (0 conflicts),
// realized as TWO independent 16KB half-buffers staged per step.
// 128 pix x 128 co tile, 256 thr = 4 waves (2Mx2N), 512 blocks (2/CU), LDS 64KB.
__global__ __launch_bounds__(256, 2) void gemm_k(
    const u16*   __restrict__ abf,    // [8][66][66][512] bf16 padded
    const u16*   __restrict__ wt,     // [9][256][512] bf16
    const float* __restrict__ bb,     // [256]
    u16*         __restrict__ feat)   // [32768][256] bf16
{
    __shared__ u16 As[2][128 * 64];   // 2 x 16 KB (two K-halves of one step)
    __shared__ u16 Bs[2][128 * 64];   // 2 x 16 KB

    int bid = blockIdx.x;                          // 512
    int wg  = ((bid & 7) << 6) | (bid >> 3);       // XCD swizzle: img = bid&7
    int mt  = wg >> 1, nt = wg & 1;
    int pm0 = mt << 7, cn0 = nt << 7;
    int img = mt >> 5;
    int y0  = (mt & 31) << 1;

    int tid = threadIdx.x, lane = tid & 63, w = tid >> 6;
    int wm2 = (w >> 1) << 6, wn2 = (w & 1) << 6;
    int fr = lane & 15, fg = lane >> 4;

    // staging: per half-buffer 1024 slots of 16B (4/thr); r9 layout exactly
    const u16* pA[4]; const u16* pB[4];
    int ldsOff[4];
    #pragma unroll
    for (int i = 0; i < 4; ++i) {
        int slot = i * 256 + w * 64 + lane;        // 0..1023
        int row  = slot >> 3, g = slot & 7;
        int gs   = g ^ (row & 7);                  // inverse swizzle on source
        int y = y0 + (row >> 6), x = row & 63;
        pA[i] = abf + ((size_t)((img * 66 + y) * 66 + x) << 9) + (gs << 3);
        pB[i] = wt  + ((size_t)(cn0 + row) << 9) + (gs << 3);
        ldsOff[i] = (i * 256 + w * 64) << 3;       // u16 index, wave-uniform
    }

    // fragment LDS offsets (u16 idx), stride 64: r9's zero-conflict layout
    int aoff[2][4], boff[2][4];
    #pragma unroll
    for (int kk = 0; kk < 2; ++kk)
        #pragma unroll
        for (int t = 0; t < 4; ++t) {
            int ra = wm2 + (t << 4) + fr;
            int rb = wn2 + (t << 4) + fr;
            int q  = (kk << 2) | fg;
            aoff[kk][t] = (ra << 6) + ((q ^ (ra & 7)) << 3);
            boff[kk][t] = (rb << 6) + ((q ^ (rb & 7)) << 3);
        }

    f32x4 acc[4][4] = {};

    #pragma unroll 1
    for (int kb = 0; kb < 4; ++kb) {               // 128-ci chunk, L2-hot A
        size_t kOff = (size_t)(kb << 7);
        #pragma unroll 1
        for (int pos = 0; pos < 9; ++pos) {
            int py = pos / 3, px = pos - py * 3;
            size_t aEl = (((size_t)(py * 66 + px)) << 9) + kOff;
            size_t bEl = (((size_t)pos) << 17) + kOff;
            // stage both 64-ci halves into separate buffers (8 loads/thread)
            #pragma unroll
            for (int h = 0; h < 2; ++h) {
                size_t soA = aEl + ((size_t)h << 6);
                size_t soB = bEl + ((size_t)h << 6);
                #pragma unroll
                for (int i = 0; i < 4; ++i) gload_lds16(pA[i] + soA, &As[h][ldsOff[i]]);
                #pragma unroll
                for (int i = 0; i < 4; ++i) gload_lds16(pB[i] + soB, &Bs[h][ldsOff[i]]);
            }
            __syncthreads();                       // drains all 16 loads

            // 64 MFMA/wave between barriers (4 groups of 16)
            #pragma unroll
            for (int h = 0; h < 2; ++h)
                #pragma unroll
                for (int kk = 0; kk < 2; ++kk) {
                    bfrag av[4], bv[4];
                    #pragma unroll
                    for (int t = 0; t < 4; ++t) {
                        av[t] = *(const bfrag*)&As[h][aoff[kk][t]];
                        bv[t] = *(const bfrag*)&Bs[h][boff[kk][t]];
                    }
                    #pragma unroll
                    for (int mi = 0; mi < 4; ++mi)
                        #pragma unroll
                        for (int ni = 0; ni < 4; ++ni)
                            acc[mi][ni] = __builtin_amdgcn_mfma_f32_16x16x32_bf16(
                                av[mi], bv[ni], acc[mi][ni], 0, 0, 0);
                }
            __syncthreads();                       // reads done before next stage
        }
    }

    // epilogue: bias + relu -> feat[pix][co] bf16
    #pragma unroll
    for (int ni = 0; ni < 4; ++ni) {
        int co = cn0 + wn2 + (ni << 4) + fr;
        float bias = bb[co];
        #pragma unroll
        for (int mi = 0; mi < 4; ++mi) {
            int pixb = pm0 + wm2 + (mi << 4) + (fg << 2);
            #pragma unroll
            for (int r = 0; r < 4; ++r) {
                float v = fmaxf(acc[mi][ni][r] + bias, 0.f);
                feat[(size_t)(pixb + r) * 256 + co] = f2bf(v);
            }
        }
    }
}

// ---------------- head: MFMA GEMM [64pix x 48ch x 256] + sigmoid/mask/pack
__global__ __launch_bounds__(256, 2) void head_k(
    const u16*   __restrict__ feat,   // [32768][256] bf16
    const u16*   __restrict__ wh,     // [64][256] bf16 (45 live)
    const float* __restrict__ bc,     // [9]
    const float* __restrict__ br,     // [36]
    float*       __restrict__ out)    // [32768,45]
{
    __shared__ union {
        u16   ft[64 * 256];           // 32 KB, granule-swizzled
        float raw[64 * 45];           // 11.5 KB
    } sm;

    int bid = blockIdx.x;                          // 512
    int wg  = ((bid & 7) << 6) | (bid >> 3);       // img = bid&7
    int pb  = wg << 6;                             // pixel base

    int tid = threadIdx.x, lane = tid & 63, w = tid >> 6;
    int fr = lane & 15, fg = lane >> 4;
    int wm = w << 4;                               // wave's 16-pix slice

    bfrag bv[3][8];
    #pragma unroll
    for (int nt = 0; nt < 3; ++nt)
        #pragma unroll
        for (int kk = 0; kk < 8; ++kk)
            bv[nt][kk] = *(const bfrag*)(wh + ((nt << 4) + fr) * 256 + (kk << 5) + (fg << 3));

    const u16* fbase = feat + ((size_t)pb << 8);
    #pragma unroll
    for (int i = 0; i < 8; ++i) {
        int slot = i * 256 + tid;                  // 0..2047
        int row  = slot >> 5, g = slot & 31;
        int gs   = g ^ (row & 7);
        gload_lds16(fbase + (row << 8) + (gs << 3), &sm.ft[(i * 256 + w * 64) << 3]);
    }
    __syncthreads();

    f32x4 acc[3] = {};
    #pragma unroll
    for (int kk = 0; kk < 8; ++kk) {
        int row = wm + fr;
        int ga  = (kk << 2) | fg;
        bfrag av = *(const bfrag*)&sm.ft[(row << 8) + ((ga ^ (row & 7)) << 3)];
        #pragma unroll
        for (int nt = 0; nt < 3; ++nt)
            acc[nt] = __builtin_amdgcn_mfma_f32_16x16x32_bf16(av, bv[nt][kk], acc[nt], 0, 0, 0);
    }
    __syncthreads();                               // ft reads done (union reuse)

    #pragma unroll
    for (int nt = 0; nt < 3; ++nt) {
        int ch = (nt << 4) + fr;
        if (ch < 45) {
            float bias = (ch < 36) ? br[ch] : bc[ch - 36];
            int pix = wm + (fg << 2);
            #pragma unroll
            for (int r = 0; r < 4; ++r)
                sm.raw[(pix + r) * 45 + ch] = acc[nt][r] + bias;
        }
    }
    __syncthreads();

    {
        int pix = tid >> 2, q = tid & 3;
        const float* rp = &sm.raw[pix * 45];
        float* op = out + (size_t)(pb + pix) * 45;
        int na = (q == 3) ? 3 : 2;
        int a0 = (q == 3) ? 6 : (q << 1);
        for (int t = 0; t < na; ++t) {
            int a = a0 + t;
            float lg  = rp[36 + a];
            float obj = 1.f / (1.f + __expf(-lg));
            float b0 = rp[4*a], b1 = rp[4*a+1], b2 = rp[4*a+2], b3 = rp[4*a+3];
            bool m = (obj > 0.7f) && (b2 > 10.f) && (b3 > 10.f);
            op[4*a    ] = m ? b0 : 0.f;
            op[4*a + 1] = m ? b1 : 0.f;
            op[4*a + 2] = m ? b2 : 0.f;
            op[4*a + 3] = m ? b3 : 0.f;
            op[36 + a ] = obj;
        }
    }
}

// ================= fallback (r6): fused conv+head, needs only wt (or nothing)
__global__ __launch_bounds__(256) void prep_w_k(const float* __restrict__ wb,
                                                u16* __restrict__ wt)
{
    int i  = blockIdx.x * 256 + threadIdx.x;
    int ci = i & 511;
    int co = (i >> 9) & 255;
    int pos = i >> 17;
    wt[i] = f2bf(wb[(size_t)((pos << 9) + ci) * 256 + co]);
}

union FbSmem {
    u16   hal[3 * 66 * 64];
    u16   ft[256][64];
    float raw[64 * 45];
};

template<int WMODE>
__global__ __launch_bounds__(256, 2) void fb_k(
    const float* __restrict__ data, const u16* __restrict__ wt,
    const float* __restrict__ wb, const float* __restrict__ bb,
    const float* __restrict__ wc, const float* __restrict__ bc,
    const float* __restrict__ wr, const float* __restrict__ br,
    float* __restrict__ out)
{
    __shared__ FbSmem sm;
    int bid = blockIdx.x;
    int wg  = ((bid & 7) << 6) | (bid >> 3);
    int pm0 = wg << 6;
    int img = wg >> 6;
    int y0  = wg & 63;
    int tid = threadIdx.x, lane = tid & 63, wid = tid >> 6;
    int wn = wid << 6;
    int fr = lane & 15, fg = lane >> 4;
    f32x4 acc[4][4] = {};

    #pragma unroll 1
    for (int cb = 0; cb < 8; ++cb) {
        __syncthreads();
        #pragma unroll
        for (int t = 0; t < 3; ++t) {
            int lin = t * 256 + tid;
            int row = lin >> 8, col = (lin >> 2) & 63, cq = lin & 3;
            int sy = y0 + row - 1;
            bool ok = (sy >= 0) && (sy < 64);
            float4 v0, v1, v2, v3;
            if (ok) {
                const float4* s = (const float4*)(data +
                    ((size_t)((img << 12) + (sy << 6) + col) << 9) + (cb << 6) + (cq << 4));
                v0 = s[0]; v1 = s[1]; v2 = s[2]; v3 = s[3];
            } else { v0 = v1 = v2 = v3 = make_float4(0.f, 0.f, 0.f, 0.f); }
            int hc = col + 1;
            u16* base = &sm.hal[(row * 66 + hc) << 6];
            int g0 = ((cq << 1) | 0) ^ (hc & 7);
            int g1 = ((cq << 1) | 1) ^ (hc & 7);
            *(uint4*)&base[g0 << 3] = make_uint4(pk2(v0.x,v0.y), pk2(v0.z,v0.w),
                                                 pk2(v1.x,v1.y), pk2(v1.z,v1.w));
            *(uint4*)&base[g1 << 3] = make_uint4(pk2(v2.x,v2.y), pk2(v2.z,v2.w),
                                                 pk2(v3.x,v3.y), pk2(v3.z,v3.w));
        }
        if (tid < 48) {
            int zr = tid >> 4, zrem = tid & 15;
            int zc = (zrem >> 3) ? 65 : 0, zg = zrem & 7;
            *(uint4*)&sm.hal[(((zr * 66 + zc) << 3) | zg) << 3] = make_uint4(0,0,0,0);
        }
        __syncthreads();

        #pragma unroll
        for (int pos = 0; pos < 9; ++pos) {
            int dy = pos / 3 - 1, dx = pos % 3 - 1;
            bfrag bv[2][4];
            if (WMODE == 0) {
                #pragma unroll
                for (int kk = 0; kk < 2; ++kk)
                    #pragma unroll
                    for (int i = 0; i < 4; ++i)
                        bv[kk][i] = *(const bfrag*)(wt + ((size_t)pos << 17) +
                            ((size_t)(wn + (i << 4) + fr) << 9) + (cb << 6) +
                            (kk << 5) + (fg << 3));
            } else {
                #pragma unroll
                for (int kk = 0; kk < 2; ++kk)
                    #pragma unroll
                    for (int i = 0; i < 4; ++i) {
                        int co = wn + (i << 4) + fr;
                        const float* s = wb +
                            (size_t)((pos << 9) + (cb << 6) + (kk << 5) + (fg << 3)) * 256 + co;
                        union { short sh[8]; bfrag v; } tb;
                        #pragma unroll
                        for (int j = 0; j < 8; ++j) tb.sh[j] = (short)f2bf(s[(size_t)j << 8]);
                        bv[kk][i] = tb.v;
                    }
            }
            int hr = dy + 1;
            bfrag av[2][4];
            #pragma unroll
            for (int kk = 0; kk < 2; ++kk)
                #pragma unroll
                for (int i = 0; i < 4; ++i) {
                    int hc = (i << 4) + fr + dx + 1;
                    int g  = ((kk << 2) | fg) ^ (hc & 7);
                    av[kk][i] = *(const bfrag*)&sm.hal[(((hr * 66 + hc) << 3) | g) << 3];
                }
            #pragma unroll
            for (int kk = 0; kk < 2; ++kk)
                #pragma unroll
                for (int mi = 0; mi < 4; ++mi)
                    #pragma unroll
                    for (int ni = 0; ni < 4; ++ni)
                        acc[mi][ni] = __builtin_amdgcn_mfma_f32_16x16x32_bf16(
                            av[kk][mi], bv[kk][ni], acc[mi][ni], 0, 0, 0);
        }
    }
    __syncthreads();

    #pragma unroll
    for (int ni = 0; ni < 4; ++ni) {
        int co = wn + (ni << 4) + fr;
        float bias = bb[co];
        int rot = (co & 15) << 2;
        #pragma unroll
        for (int mi = 0; mi < 4; ++mi) {
            int pb  = (mi << 4) + (fg << 2);
            int col = (pb + rot) & 63;
            float r0 = fmaxf(acc[mi][ni][0] + bias, 0.f);
            float r1 = fmaxf(acc[mi][ni][1] + bias, 0.f);
            float r2 = fmaxf(acc[mi][ni][2] + bias, 0.f);
            float r3 = fmaxf(acc[mi][ni][3] + bias, 0.f);
            *(uint2*)&sm.ft[co][col] = make_uint2(pk2(r0, r1), pk2(r2, r3));
        }
    }
    __syncthreads();

    int wchx = __builtin_amdgcn_readfirstlane(wid) * 12;
    float a12[12];
    #pragma unroll
    for (int j = 0; j < 12; ++j) {
        int ch = wchx + j;
        a12[j] = (ch < 36) ? br[ch] : ((ch < 45) ? bc[ch - 36] : 0.f);
    }
    #pragma unroll 4
    for (int c = 0; c < 256; ++c) {
        int col = (lane + ((c & 15) << 2)) & 63;
        float f = bf2f(sm.ft[c][col]);
        #pragma unroll
        for (int j = 0; j < 12; ++j) {
            int ch = wchx + j;
            if (ch < 36)      a12[j] = fmaf(f, wr[c * 36 + ch], a12[j]);
            else if (ch < 45) a12[j] = fmaf(f, wc[c * 9 + ch - 36], a12[j]);
        }
    }
    __syncthreads();
    #pragma unroll
    for (int j = 0; j < 12; ++j) {
        int ch = wchx + j;
        if (ch < 45) sm.raw[lane * 45 + ch] = a12[j];
    }
    __syncthreads();
    {
        int pix = tid >> 2, q = tid & 3;
        const float* rp = &sm.raw[pix * 45];
        float* op = out + (size_t)(pm0 + pix) * 45;
        int na = (q == 3) ? 3 : 2;
        int a0 = (q == 3) ? 6 : (q << 1);
        for (int t = 0; t < na; ++t) {
            int a = a0 + t;
            float lg  = rp[36 + a];
            float obj = 1.f / (1.f + __expf(-lg));
            float b0 = rp[4*a], b1 = rp[4*a+1], b2 = rp[4*a+2], b3 = rp[4*a+3];
            bool m = (obj > 0.7f) && (b2 > 10.f) && (b3 > 10.f);
            op[4*a    ] = m ? b0 : 0.f;
            op[4*a + 1] = m ? b1 : 0.f;
            op[4*a + 2] = m ? b2 : 0.f;
            op[4*a + 3] = m ? b3 : 0.f;
            op[36 + a ] = obj;
        }
    }
}

extern "C" void kernel_launch(void* const* d_in, const int* in_sizes, int n_in,
                              void* d_out, int out_size, void* d_ws, size_t ws_size,
                              hipStream_t stream)
{
    const float* data = (const float*)d_in[0];
    const float* wb   = (const float*)d_in[1];
    const float* bb   = (const float*)d_in[2];
    const float* wc   = (const float*)d_in[3];
    const float* bcl  = (const float*)d_in[4];
    const float* wr   = (const float*)d_in[5];
    const float* brg  = (const float*)d_in[6];
    float* out = (float*)d_out;

    const size_t ABF_B  = (size_t)8 * 66 * 66 * 512 * 2;   // 35,684,352
    const size_t WT_B   = (size_t)9 * 256 * 512 * 2;       //  2,359,296
    const size_t FEAT_B = (size_t)32768 * 256 * 2;         // 16,777,216
    const size_t WH_B   = (size_t)64 * 256 * 2;            //     32,768

    if (ws_size >= ABF_B + WT_B + FEAT_B + WH_B) {
        u16* abf  = (u16*)d_ws;
        u16* wt   = (u16*)((char*)d_ws + ABF_B);
        u16* feat = (u16*)((char*)d_ws + ABF_B + WT_B);
        u16* wh   = (u16*)((char*)d_ws + ABF_B + WT_B + FEAT_B);
        prep_all_k<<<13384, 256, 0, stream>>>(data, wb, wc, wr, abf, wt, wh);
        gemm_k<<<512, 256, 0, stream>>>(abf, wt, bb, feat);
        head_k<<<512, 256, 0, stream>>>(feat, wh, bcl, brg, out);
    } else if (ws_size >= WT_B) {
        u16* wt = (u16*)d_ws;
        prep_w_k<<<4608, 256, 0, stream>>>(wb, wt);
        fb_k<0><<<512, 256, 0, stream>>>(data, wt, wb, bb, wc, bcl, wr, brg, out);
    } else {
        fb_k<1><<<512, 256, 0, stream>>>(data, (const u16*)nullptr, wb,
                                         bb, wc, bcl, wr, brg, out);
    }
}